// Round 4
// baseline (52.555 us; speedup 1.0000x reference)
//
#include <hip/hip_runtime.h>

// Per-channel piecewise-linear calibration, real part only (out_size == N).
// x_real: [B=4, C=128, H=256, W=256] f32; xp,yp: [C=128, K=101] f32, xp sorted.

#define K_BP    101
#define K_PAD   128
#define NCH     128
#define HW      65536
#define NBINS   512
#define BLK     256
#define CPB     8192                  // elements per block (8 chunks/plane)
#define ITERS   (CPB / (BLK * 4))     // 8 iters, 4 floats per thread per iter

typedef float f32x4 __attribute__((ext_vector_type(4)));   // clang vector: nt-store OK

__device__ __forceinline__ int bsearch_right(float v, const float* __restrict__ xp_s) {
    // count(xp <= v) over the 128-padded (+inf) array, then segment clamp.
    int lo = 0;
    #pragma unroll
    for (int step = 64; step >= 1; step >>= 1) {
        lo += (xp_s[lo + step - 1] <= v) ? step : 0;
    }
    int j = lo - 1;
    j = j < 0 ? 0 : j;
    j = j > (K_BP - 2) ? (K_BP - 2) : j;
    return j;
}

__device__ __forceinline__ float pwl_eval(float x, float xmin, float invw,
                                          const float* __restrict__ xp_s,
                                          const float4* __restrict__ seg_s,
                                          const unsigned char* __restrict__ lut) {
    int bin = (int)((x - xmin) * invw);
    bin = bin < 0 ? 0 : bin;
    bin = bin > (NBINS - 1) ? (NBINS - 1) : bin;
    int j = lut[bin];
    // forward fix-up: hint is a lower bound (up to FP rounding at bin edges)
    while (j < (K_BP - 2) && x >= xp_s[j + 1]) ++j;
    // backward guard: bulletproof against bin-boundary FP rounding
    while (j > 0 && x < xp_s[j]) --j;
    float4 s = seg_s[j];                 // (x0, y0, slope, _)
    return fmaf(x - s.x, s.z, s.y);
}

__global__ __launch_bounds__(BLK) void pwl_real_kernel(
    const float* __restrict__ xr,
    const float* __restrict__ xp, const float* __restrict__ yp,
    float* __restrict__ out)
{
    __shared__ float         xp_s[K_PAD];
    __shared__ float4        seg_s[K_BP - 1];
    __shared__ unsigned char lut[NBINS];

    const int t     = threadIdx.x;
    const int bid   = blockIdx.x;
    const int plane = bid >> 3;            // 8 blocks per (b,c) plane
    const int chunk = bid & 7;
    const int c     = plane & (NCH - 1);
    const unsigned int base = (unsigned int)plane * HW + (unsigned int)chunk * CPB;

    // Stage breakpoints (+inf pad so count(xp<=v) ignores the pad).
    if (t < K_PAD) {
        xp_s[t] = (t < K_BP) ? xp[c * K_BP + t] : __builtin_inff();
    }
    __syncthreads();

    // Per-segment (x0, y0, slope): same arithmetic as the reference.
    if (t < K_BP - 1) {
        float y0 = yp[c * K_BP + t];
        float y1 = yp[c * K_BP + t + 1];
        float x0 = xp_s[t];
        float x1 = xp_s[t + 1];
        seg_s[t] = make_float4(x0, y0, (y1 - y0) / (x1 - x0), 0.0f);
    }

    const float xmin = xp_s[0];
    const float xmax = xp_s[K_BP - 1];
    const float w    = (xmax - xmin) * (1.0f / NBINS);
    const float invw = (float)NBINS / (xmax - xmin);

    // Build segment-hint LUT: lut[b] = segment containing the bin's left edge.
    #pragma unroll
    for (int b = t; b < NBINS; b += BLK) {
        float bl = fmaf((float)b, w, xmin);
        lut[b] = (unsigned char)bsearch_right(bl, xp_s);
    }
    __syncthreads();

    #pragma unroll
    for (int it = 0; it < ITERS; ++it) {
        const unsigned int g = base + (unsigned int)it * (BLK * 4) + (unsigned int)t * 4;
        f32x4 v = *reinterpret_cast<const f32x4*>(xr + g);
        f32x4 o;
        o.x = pwl_eval(v.x, xmin, invw, xp_s, seg_s, lut);
        o.y = pwl_eval(v.y, xmin, invw, xp_s, seg_s, lut);
        o.z = pwl_eval(v.z, xmin, invw, xp_s, seg_s, lut);
        o.w = pwl_eval(v.w, xmin, invw, xp_s, seg_s, lut);
        // Streaming store: don't allocate output in L3 -> keep x_real resident.
        __builtin_nontemporal_store(o, reinterpret_cast<f32x4*>(out + g));
    }
}

extern "C" void kernel_launch(void* const* d_in, const int* in_sizes, int n_in,
                              void* d_out, int out_size, void* d_ws, size_t ws_size,
                              hipStream_t stream) {
    const float* xr = (const float*)d_in[0];
    const float* xp = (const float*)d_in[2];
    const float* yp = (const float*)d_in[3];
    float* out = (float*)d_out;

    const long long N = (long long)in_sizes[0];   // 33,554,432
    const int blocks = (int)(N / CPB);            // 4096
    pwl_real_kernel<<<dim3(blocks), dim3(BLK), 0, stream>>>(xr, xp, yp, out);
}